// Round 17
// baseline (166.675 us; speedup 1.0000x reference)
//
#include <hip/hip_runtime.h>

#define HW 4096
#define NC 512

using f32x4  = __attribute__((ext_vector_type(4))) float;
using bf16x8 = __attribute__((ext_vector_type(8))) short;
using u32x4  = __attribute__((ext_vector_type(4))) unsigned;

__device__ __forceinline__ unsigned short f2bf(float x) {
    unsigned u = __float_as_uint(x);
    unsigned r = (u + 0x7FFF + ((u >> 16) & 1)) >> 16;   // RNE
    return (unsigned short)r;
}
__device__ __forceinline__ float bf2f(unsigned short v) {
    return __uint_as_float(((unsigned)v) << 16);
}
__device__ __forceinline__ float blo(unsigned u) { return __uint_as_float(u << 16); }
__device__ __forceinline__ float bhi(unsigned u) { return __uint_as_float(u & 0xFFFF0000u); }

#define GLDS16(g, l) __builtin_amdgcn_global_load_lds( \
    (const __attribute__((address_space(1))) void*)(g), \
    (__attribute__((address_space(3))) void*)(l), 16, 0, 0)

// ---------- Kernel 0: transpose+convert src[C][HW] f32 -> dst[HW][C] bf16,
// with masksum fused as grid slice z==2 (single active block).
__global__ __launch_bounds__(256) void transconv_kernel(const float* __restrict__ content,
                                                        const float* __restrict__ style,
                                                        unsigned short* __restrict__ cT,
                                                        unsigned short* __restrict__ sT,
                                                        const float* __restrict__ mask,
                                                        float* __restrict__ scalars) {
    if (blockIdx.z == 2) {
        if (blockIdx.x || blockIdx.y) return;
        __shared__ float s[256];
        const int tid = threadIdx.x;
        float v = 0.f;
        for (int k = tid; k < HW; k += 256) v += mask[k];
        s[tid] = v;
        __syncthreads();
        for (int off = 128; off > 0; off >>= 1) {
            if (tid < off) s[tid] += s[tid + off];
            __syncthreads();
        }
        if (tid == 0) {
            scalars[0] = s[0] * 512.0f;       // mask_sum * C
            scalars[1] = 0.f;                 // loss accumulator
            ((unsigned*)scalars)[2] = 0u;     // done-block counter
        }
        return;
    }
    const float* src = blockIdx.z ? style : content;
    unsigned short* dst = blockIdx.z ? sT : cT;
    __shared__ float tile[32][33];
    const int i0 = blockIdx.x * 32;   // hw
    const int c0 = blockIdx.y * 32;   // channel
    const int tx = threadIdx.x & 31, ty = threadIdx.x >> 5;   // ty 0..7
#pragma unroll
    for (int r = 0; r < 32; r += 8)
        tile[ty + r][tx] = src[(size_t)(c0 + ty + r) * HW + i0 + tx];
    __syncthreads();
#pragma unroll
    for (int r = 0; r < 32; r += 8)
        dst[(size_t)(i0 + ty + r) * NC + c0 + tx] = f2bf(tile[tx][ty + r]);
}

// ---------- Kernel 1: Bb[i][j] = sum_c cT[i][c]*sT[j][c]  (bf16 MFMA, bf16 out)
__global__ __launch_bounds__(256) void gemmB_mfma(const unsigned short* __restrict__ cT,
                                                  const unsigned short* __restrict__ sT,
                                                  unsigned short* __restrict__ Bb) {
    __shared__ unsigned short As[128 * 32];
    __shared__ unsigned short Bs[128 * 32];
    const int tid = threadIdx.x;
    const int wid = tid >> 6, lane = tid & 63;
    const int wr = wid >> 1, wc = wid & 1;
    const int bi = blockIdx.y * 128, bj = blockIdx.x * 128;
    f32x4 acc[4][4] = {};

    const int r0 = tid >> 2,         k80 = (tid & 3) << 3;
    const int r1 = (tid + 256) >> 2, k81 = ((tid + 256) & 3) << 3;
    unsigned short* dst0 = &As[0] + (size_t)(wid * 64) * 8;
    unsigned short* dst1 = &As[0] + (size_t)(256 + wid * 64) * 8;
    unsigned short* dstB0 = &Bs[0] + (size_t)(wid * 64) * 8;
    unsigned short* dstB1 = &Bs[0] + (size_t)(256 + wid * 64) * 8;

    for (int k0 = 0; k0 < NC; k0 += 32) {
        GLDS16(&cT[(size_t)(bi + r0) * NC + k0 + k80], dst0);
        GLDS16(&cT[(size_t)(bi + r1) * NC + k0 + k81], dst1);
        GLDS16(&sT[(size_t)(bj + r0) * NC + k0 + k80], dstB0);
        GLDS16(&sT[(size_t)(bj + r1) * NC + k0 + k81], dstB1);
        __syncthreads();
        bf16x8 a_frag[4], b_frag[4];
#pragma unroll
        for (int m = 0; m < 4; ++m)
            a_frag[m] = *(const bf16x8*)&As[(wr * 64 + m * 16 + (lane & 15)) * 32 + (lane >> 4) * 8];
#pragma unroll
        for (int n = 0; n < 4; ++n)
            b_frag[n] = *(const bf16x8*)&Bs[(wc * 64 + n * 16 + (lane & 15)) * 32 + (lane >> 4) * 8];
#pragma unroll
        for (int m = 0; m < 4; ++m)
#pragma unroll
            for (int n = 0; n < 4; ++n)
                acc[m][n] = __builtin_amdgcn_mfma_f32_16x16x32_bf16(a_frag[m], b_frag[n], acc[m][n], 0, 0, 0);
        __syncthreads();
    }
#pragma unroll
    for (int m = 0; m < 4; ++m)
#pragma unroll
        for (int n = 0; n < 4; ++n)
#pragma unroll
            for (int r = 0; r < 4; ++r) {
                int row = bi + wr * 64 + m * 16 + (lane >> 4) * 4 + r;
                int col = bj + wc * 64 + n * 16 + (lane & 15);
                Bb[(size_t)row * HW + col] = f2bf(acc[m][n][r]);
            }
}

// ---------- Kernel 2a: separable x-pass, 2 output rows per thread ------------
// Rows r0 (even), r0+1 share loaded rows r0-1..r0+2: 16 loads per 2 outputs.
// y-masks: out1 lo needs xr>0; out1 hi always valid (xr even <=62);
//          out2 lo always valid; out2 hi needs xr<62.
__global__ __launch_bounds__(256) void stencilx_kernel(const unsigned short* __restrict__ Bb,
                                                       unsigned short* __restrict__ Dx) {
    const int t = threadIdx.x;
    const int r0 = blockIdx.x * 4 + (t >> 7) * 2;   // even output row
    const int base = (t & 127) * 32;
    const int xr = r0 & 63;                          // even
    const bool okm1 = xr > 0;
    const bool okp2 = xr < 62;
    const bool typeB = (base & 63) != 0;             // base%64==32

    const unsigned short* pR1 = Bb + (size_t)r0 * HW + base;
    const unsigned short* pR0 = pR1 - HW;
    const unsigned short* pR2 = pR1 + HW;
    const unsigned short* pR3 = pR2 + HW;

    const u32x4 Z = {0, 0, 0, 0};
    u32x4 R0[4], R1[4], R2[4], R3[4];
#pragma unroll
    for (int k = 0; k < 4; ++k) {
        R1[k] = *(const u32x4*)(pR1 + 8 * k);
        R2[k] = *(const u32x4*)(pR2 + 8 * k);
        R0[k] = okm1 ? *(const u32x4*)(pR0 + 8 * k) : Z;
        R3[k] = okp2 ? *(const u32x4*)(pR3 + 8 * k) : Z;
    }
    // edge scalars (outside the 32-col span); type A never needs left (x_j=0
    // masked), type B never needs right (x_j=63 masked).
    float eL1 = (typeB && okm1) ? bf2f(pR0[-1]) : 0.f;
    float eR1 = (!typeB)        ? bf2f(pR2[32]) : 0.f;
    float eL2 = (typeB)         ? bf2f(pR1[-1]) : 0.f;
    float eR2 = (!typeB && okp2)? bf2f(pR3[32]) : 0.f;

    float f0[32], f1[32], f2[32], f3[32];
#pragma unroll
    for (int k = 0; k < 4; ++k)
#pragma unroll
        for (int d = 0; d < 4; ++d) {
            int e = k * 8 + d * 2;
            f0[e] = blo(R0[k][d]); f0[e + 1] = bhi(R0[k][d]);
            f1[e] = blo(R1[k][d]); f1[e + 1] = bhi(R1[k][d]);
            f2[e] = blo(R2[k][d]); f2[e + 1] = bhi(R2[k][d]);
            f3[e] = blo(R3[k][d]); f3[e + 1] = bhi(R3[k][d]);
        }
    unsigned short o1[32], o2[32];
#pragma unroll
    for (int e = 0; e < 32; ++e) {
        float lo1 = (e == 0) ? eL1 : f0[e - 1];
        float hi1 = (e == 31) ? eR1 : f2[e + 1];
        o1[e] = f2bf(f1[e] + lo1 + hi1);
        float lo2 = (e == 0) ? eL2 : f1[e - 1];
        float hi2 = (e == 31) ? eR2 : f3[e + 1];
        o2[e] = f2bf(f2[e] + lo2 + hi2);
    }
    unsigned short* q1 = Dx + (size_t)r0 * HW + base;
    unsigned short* q2 = q1 + HW;
#pragma unroll
    for (int k = 0; k < 4; ++k) {
        *(u32x4*)(q1 + 8 * k) = *(u32x4*)&o1[k * 8];
        *(u32x4*)(q2 + 8 * k) = *(u32x4*)&o2[k * 8];
    }
}

// ---------- Kernel 2b: y-pass + first-max argmax over j ----------------------
__global__ __launch_bounds__(256) void stencily_argmax_kernel(const unsigned short* __restrict__ Dx,
                                                              int* __restrict__ corr) {
    const int i = blockIdx.x;
    const int yi = i >> 6;
    const int t = threadIdx.x;
    const bool okm = yi > 0, okp = yi < 63;
    const u32x4 Z = {0, 0, 0, 0};
    float best = -1e30f;
    int bestj = 0;
#pragma unroll
    for (int cc = 0; cc < 2; ++cc) {
        const int c0 = t * 16 + cc * 8;
        const unsigned short* pm = Dx + (size_t)i * HW + c0;
        const bool my = okm && (c0 >= 64);
        const bool mp = okp && (c0 < 4032);
        u32x4 m_ = *(const u32x4*)pm;
        u32x4 l_ = my ? *(const u32x4*)(pm - (size_t)64 * HW - 64) : Z;
        u32x4 h_ = mp ? *(const u32x4*)(pm + (size_t)64 * HW + 64) : Z;
#pragma unroll
        for (int d = 0; d < 4; ++d) {
            float s0 = blo(m_[d]) + blo(l_[d]) + blo(h_[d]);
            float s1 = bhi(m_[d]) + bhi(l_[d]) + bhi(h_[d]);
            int j0 = c0 + 2 * d;
            if (s0 > best) { best = s0; bestj = j0; }
            if (s1 > best) { best = s1; bestj = j0 + 1; }
        }
    }
    __shared__ float sv[256];
    __shared__ int si[256];
    sv[t] = best; si[t] = bestj;
    __syncthreads();
    for (int off = 128; off > 0; off >>= 1) {
        if (t < off) {
            float v2 = sv[t + off]; int i2 = si[t + off];
            if (v2 > sv[t] || (v2 == sv[t] && i2 < si[t])) { sv[t] = v2; si[t] = i2; }
        }
        __syncthreads();
    }
    if (t == 0) corr[i] = si[0];
}

// ---------- Kernel 4: fib = bf16(input*mask); fmb = bf16(style[:,corr]*mask) -
// 8 elems/thread.
__global__ __launch_bounds__(256) void prep_kernel(const float* __restrict__ input,
                                                   const float* __restrict__ style,
                                                   const float* __restrict__ mask,
                                                   const int* __restrict__ corr,
                                                   unsigned short* __restrict__ fib,
                                                   unsigned short* __restrict__ fmb) {
    const int g8 = (blockIdx.x * 256 + threadIdx.x) * 8;
    const int hw = g8 & 4095;
    const int c = g8 >> 12;
    float4 in0 = *(const float4*)&input[g8];
    float4 in1 = *(const float4*)&input[g8 + 4];
    float4 mk0 = *(const float4*)&mask[hw];
    float4 mk1 = *(const float4*)&mask[hw + 4];
    const float* srow = &style[(size_t)c << 12];
    unsigned short vi[8], vm[8];
    vi[0] = f2bf(in0.x * mk0.x); vi[1] = f2bf(in0.y * mk0.y);
    vi[2] = f2bf(in0.z * mk0.z); vi[3] = f2bf(in0.w * mk0.w);
    vi[4] = f2bf(in1.x * mk1.x); vi[5] = f2bf(in1.y * mk1.y);
    vi[6] = f2bf(in1.z * mk1.z); vi[7] = f2bf(in1.w * mk1.w);
    vm[0] = f2bf(srow[corr[hw + 0]] * mk0.x);
    vm[1] = f2bf(srow[corr[hw + 1]] * mk0.y);
    vm[2] = f2bf(srow[corr[hw + 2]] * mk0.z);
    vm[3] = f2bf(srow[corr[hw + 3]] * mk0.w);
    vm[4] = f2bf(srow[corr[hw + 4]] * mk1.x);
    vm[5] = f2bf(srow[corr[hw + 5]] * mk1.y);
    vm[6] = f2bf(srow[corr[hw + 6]] * mk1.z);
    vm[7] = f2bf(srow[corr[hw + 7]] * mk1.w);
    *(u32x4*)&fib[g8] = *(u32x4*)vi;
    *(u32x4*)&fmb[g8] = *(u32x4*)vm;
}

// ---------- Kernel 5: gram-DIFF partials, upper-triangle 64x64 tiles ---------
// grid (36, 8): tile t -> (ti<=tj) 64x64 block of (Gi - Gm); z-chunk K=512.
__global__ __launch_bounds__(256) void gram_diff_mfma(const unsigned short* __restrict__ fib,
                                                      const unsigned short* __restrict__ fmb,
                                                      float* __restrict__ P) {
    __shared__ unsigned short Ai[64 * 32], Bi[64 * 32], Am[64 * 32], Bm[64 * 32];
    const int tid = threadIdx.x;
    const int wid = tid >> 6, lane = tid & 63;
    const int wr = wid >> 1, wc = wid & 1;
    int q = blockIdx.x, ti = 0;
    while (q >= 8 - ti) { q -= 8 - ti; ++ti; }
    const int tj = ti + q;
    const int row0 = ti * 64, col0 = tj * 64;
    const int kz = blockIdx.y * 512;
    f32x4 acci[2][2] = {}, accm[2][2] = {};

    const int srow = tid >> 2, skoff = (tid & 3) << 3;
    unsigned short* bA = &Ai[wid * 512];
    unsigned short* bB = &Bi[wid * 512];
    unsigned short* bC = &Am[wid * 512];
    unsigned short* bD = &Bm[wid * 512];

    for (int k0 = 0; k0 < 512; k0 += 32) {
        const int ka = kz + k0 + skoff;
        GLDS16(&fib[(size_t)(row0 + srow) * HW + ka], bA);
        GLDS16(&fib[(size_t)(col0 + srow) * HW + ka], bB);
        GLDS16(&fmb[(size_t)(row0 + srow) * HW + ka], bC);
        GLDS16(&fmb[(size_t)(col0 + srow) * HW + ka], bD);
        __syncthreads();
        bf16x8 ai[2], bi_[2], am[2], bm[2];
#pragma unroll
        for (int m = 0; m < 2; ++m) {
            int off = (wr * 32 + m * 16 + (lane & 15)) * 32 + (lane >> 4) * 8;
            ai[m] = *(const bf16x8*)&Ai[off];
            am[m] = *(const bf16x8*)&Am[off];
        }
#pragma unroll
        for (int n = 0; n < 2; ++n) {
            int off = (wc * 32 + n * 16 + (lane & 15)) * 32 + (lane >> 4) * 8;
            bi_[n] = *(const bf16x8*)&Bi[off];
            bm[n] = *(const bf16x8*)&Bm[off];
        }
#pragma unroll
        for (int m = 0; m < 2; ++m)
#pragma unroll
            for (int n = 0; n < 2; ++n) {
                acci[m][n] = __builtin_amdgcn_mfma_f32_16x16x32_bf16(ai[m], bi_[n], acci[m][n], 0, 0, 0);
                accm[m][n] = __builtin_amdgcn_mfma_f32_16x16x32_bf16(am[m], bm[n], accm[m][n], 0, 0, 0);
            }
        __syncthreads();
    }
    float* Pz = P + ((size_t)blockIdx.y * 36 + blockIdx.x) * 4096;
#pragma unroll
    for (int m = 0; m < 2; ++m)
#pragma unroll
        for (int n = 0; n < 2; ++n)
#pragma unroll
            for (int r = 0; r < 4; ++r) {
                int a_ = wr * 32 + m * 16 + (lane >> 4) * 4 + r;
                int b_ = wc * 32 + n * 16 + (lane & 15);
                Pz[a_ * 64 + b_] = acci[m][n][r] - accm[m][n][r];
            }
}

// ---------- Kernel 6: loss = sum w*(sum_z P / msum)^2, finalize fused --------
__global__ __launch_bounds__(256) void loss_final_kernel(const float* __restrict__ P,
                                                         float* __restrict__ scalars,
                                                         float* __restrict__ out) {
    const int tid = threadIdx.x;
    const int t = blockIdx.x >> 2;
    int q = t, ti = 0;
    while (q >= 8 - ti) { q -= 8 - ti; ++ti; }
    const float w = (q == 0) ? 1.0f : 2.0f;   // diagonal tile self-duplicates off-diag
    const float inv = 1.0f / scalars[0];
    float lsum = 0.f;
    const int e0 = blockIdx.x * 1024;
#pragma unroll
    for (int k = 0; k < 4; ++k) {
        const int e = e0 + k * 256 + tid;
        float g = 0.f;
#pragma unroll
        for (int z = 0; z < 8; ++z) g += P[(size_t)z * 147456 + e];
        float d = g * inv;
        lsum = fmaf(w * d, d, lsum);
    }
    __shared__ float red[256];
    red[tid] = lsum;
    __syncthreads();
    for (int off = 128; off > 0; off >>= 1) {
        if (tid < off) red[tid] += red[tid + off];
        __syncthreads();
    }
    if (tid == 0) {
        atomicAdd(&scalars[1], red[0]);
        __threadfence();
        unsigned old = atomicAdd(&((unsigned*)scalars)[2], 1u);
        if (old == 143u) {
            __threadfence();
            out[0] = *(volatile float*)&scalars[1] * (100.0f / 262144.0f);
        }
    }
}

extern "C" void kernel_launch(void* const* d_in, const int* in_sizes, int n_in,
                              void* d_out, int out_size, void* d_ws, size_t ws_size,
                              hipStream_t stream) {
    (void)in_sizes; (void)n_in; (void)out_size; (void)ws_size;
    const float* input   = (const float*)d_in[0];
    const float* style   = (const float*)d_in[1];
    const float* content = (const float*)d_in[2];
    const float* mask    = (const float*)d_in[3];
    float* out = (float*)d_out;

    // ws layout (phase-overlapped, peak 64 MB + 16 KB):
    //   phase A: cT [32,36) sT [36,40) MB     -> gemmB writes Bb [0,32)
    //   phase B: stencilx writes Dx [32,64)   (cT/sT dead)
    //   phase C: prep writes fib [0,4) fmb [4,8)      (Bb dead)
    //            gram_diff writes P [8,13)            (36*8*4096 f32 = 4.7 MB)
    //   corr int at [64MB), scalars after.
    char* base = (char*)d_ws;
    unsigned short* Bb = (unsigned short*)base;
    unsigned short* cT = (unsigned short*)(base + (((size_t)32) << 20));
    unsigned short* sT = cT + (size_t)HW * NC;
    unsigned short* Dx = (unsigned short*)(base + (((size_t)32) << 20));
    unsigned short* fib = (unsigned short*)base;
    unsigned short* fmb = fib + (size_t)NC * HW;
    float* P = (float*)(base + (((size_t)8) << 20));
    int* corr = (int*)(base + (((size_t)64) << 20));
    float* scalars = (float*)(corr + HW);

    transconv_kernel<<<dim3(128, 16, 3), 256, 0, stream>>>(content, style, cT, sT, mask, scalars);
    gemmB_mfma<<<dim3(32, 32), 256, 0, stream>>>(cT, sT, Bb);
    stencilx_kernel<<<1024, 256, 0, stream>>>(Bb, Dx);
    stencily_argmax_kernel<<<HW, 256, 0, stream>>>(Dx, corr);
    prep_kernel<<<(NC * HW / 8) / 256, 256, 0, stream>>>(input, style, mask, corr, fib, fmb);
    gram_diff_mfma<<<dim3(36, 8), 256, 0, stream>>>(fib, fmb, P);
    loss_final_kernel<<<144, 256, 0, stream>>>(P, scalars, out);
}